// Round 1
// baseline (3598.455 us; speedup 1.0000x reference)
//
#include <hip/hip_runtime.h>
#include <cmath>

#define D_MODEL 1024
#define L_SEQ   2048
#define N_BATCH 4
#define N_HEAD  16
#define H_DIM   64
#define D_FF    4096
#define M_ROWS  (N_BATCH * L_SEQ)   // 8192

// ---------------------------------------------------------------------------
// Fused LayerNorm: one block per row (D=1024), 256 threads * float4
// ---------------------------------------------------------------------------
__global__ __launch_bounds__(256)
void ln_kernel(const float* __restrict__ x, const float* __restrict__ gamma,
               const float* __restrict__ beta, float* __restrict__ y)
{
    int row = blockIdx.x;
    int t = threadIdx.x;
    const float4* xr = reinterpret_cast<const float4*>(x + (size_t)row * D_MODEL);
    float4 v = xr[t];
    float s  = v.x + v.y + v.z + v.w;
    float s2 = v.x*v.x + v.y*v.y + v.z*v.z + v.w*v.w;
    #pragma unroll
    for (int off = 32; off > 0; off >>= 1) {
        s  += __shfl_down(s,  off);
        s2 += __shfl_down(s2, off);
    }
    __shared__ float red[8];
    int wid = t >> 6;
    if ((t & 63) == 0) { red[wid] = s; red[4 + wid] = s2; }
    __syncthreads();
    s  = red[0] + red[1] + red[2] + red[3];
    s2 = red[4] + red[5] + red[6] + red[7];
    float mu   = s * (1.0f / D_MODEL);
    float var  = s2 * (1.0f / D_MODEL) - mu * mu;
    float rstd = rsqrtf(var + 1e-5f);
    float4 g  = reinterpret_cast<const float4*>(gamma)[t];
    float4 bb = reinterpret_cast<const float4*>(beta)[t];
    float4 o;
    o.x = (v.x - mu) * rstd * g.x + bb.x;
    o.y = (v.y - mu) * rstd * g.y + bb.y;
    o.z = (v.z - mu) * rstd * g.z + bb.z;
    o.w = (v.w - mu) * rstd * g.w + bb.w;
    reinterpret_cast<float4*>(y + (size_t)row * D_MODEL)[t] = o;
}

// ---------------------------------------------------------------------------
// fp32 tiled GEMM: C[M,N] = A[M,K]@B[K,N] (+bias) (+relu) (+resid)
// 128x128 tile, BK=16, 256 threads, 8x8 microtile (split 64+64 to dodge
// LDS bank conflicts: pad stride 132 -> bank step 4 per row).
// ---------------------------------------------------------------------------
template<bool HAS_BIAS, bool RELU, bool RESID>
__global__ __launch_bounds__(256)
void gemm128(const float* __restrict__ A, const float* __restrict__ B,
             const float* __restrict__ bias, const float* __restrict__ resid,
             float* __restrict__ C, int M, int N, int K)
{
    constexpr int BK = 16;
    constexpr int ST = 132;          // padded LDS row stride (floats)
    __shared__ float As[BK * ST];    // [k][m]
    __shared__ float Bs[BK * ST];    // [k][n]
    int tid = threadIdx.x;
    int tx = tid & 15, ty = tid >> 4;
    int m0 = blockIdx.y * 128, n0 = blockIdx.x * 128;

    int a_row = tid >> 1,        a_k = (tid & 1) * 8;   // 128 rows x 16 k
    int b_k   = tid >> 4,        b_n = (tid & 15) * 8;  // 16 k x 128 n

    const float* Ap = A + (size_t)(m0 + a_row) * K + a_k;
    const float* Bp = B + (size_t)b_k * N + n0 + b_n;

    float c[8][8];
    #pragma unroll
    for (int i = 0; i < 8; ++i)
        #pragma unroll
        for (int j = 0; j < 8; ++j) c[i][j] = 0.0f;

    for (int kt = 0; kt < K; kt += BK) {
        float4 av0 = *reinterpret_cast<const float4*>(Ap);
        float4 av1 = *reinterpret_cast<const float4*>(Ap + 4);
        float4 bv0 = *reinterpret_cast<const float4*>(Bp);
        float4 bv1 = *reinterpret_cast<const float4*>(Bp + 4);
        __syncthreads();   // previous tile's compute done before overwrite
        As[(a_k + 0) * ST + a_row] = av0.x;
        As[(a_k + 1) * ST + a_row] = av0.y;
        As[(a_k + 2) * ST + a_row] = av0.z;
        As[(a_k + 3) * ST + a_row] = av0.w;
        As[(a_k + 4) * ST + a_row] = av1.x;
        As[(a_k + 5) * ST + a_row] = av1.y;
        As[(a_k + 6) * ST + a_row] = av1.z;
        As[(a_k + 7) * ST + a_row] = av1.w;
        *reinterpret_cast<float4*>(&Bs[b_k * ST + b_n])     = bv0;
        *reinterpret_cast<float4*>(&Bs[b_k * ST + b_n + 4]) = bv1;
        __syncthreads();
        #pragma unroll
        for (int kk = 0; kk < BK; ++kk) {
            float4 a0 = *reinterpret_cast<const float4*>(&As[kk * ST + ty * 4]);
            float4 a1 = *reinterpret_cast<const float4*>(&As[kk * ST + 64 + ty * 4]);
            float4 b0 = *reinterpret_cast<const float4*>(&Bs[kk * ST + tx * 4]);
            float4 b1 = *reinterpret_cast<const float4*>(&Bs[kk * ST + 64 + tx * 4]);
            float ar[8] = {a0.x,a0.y,a0.z,a0.w, a1.x,a1.y,a1.z,a1.w};
            float br[8] = {b0.x,b0.y,b0.z,b0.w, b1.x,b1.y,b1.z,b1.w};
            #pragma unroll
            for (int i = 0; i < 8; ++i)
                #pragma unroll
                for (int j = 0; j < 8; ++j)
                    c[i][j] = fmaf(ar[i], br[j], c[i][j]);
        }
        Ap += BK;
        Bp += (size_t)BK * N;
    }

    #pragma unroll
    for (int i = 0; i < 8; ++i) {
        int r = m0 + ((i < 4) ? (ty * 4 + i) : (64 + ty * 4 + (i - 4)));
        #pragma unroll
        for (int jh = 0; jh < 2; ++jh) {
            int cn = n0 + jh * 64 + tx * 4;
            float4 o;
            o.x = c[i][jh*4+0]; o.y = c[i][jh*4+1];
            o.z = c[i][jh*4+2]; o.w = c[i][jh*4+3];
            if (HAS_BIAS) {
                float4 bi = *reinterpret_cast<const float4*>(bias + cn);
                o.x += bi.x; o.y += bi.y; o.z += bi.z; o.w += bi.w;
            }
            if (RELU) {
                o.x = fmaxf(o.x, 0.f); o.y = fmaxf(o.y, 0.f);
                o.z = fmaxf(o.z, 0.f); o.w = fmaxf(o.w, 0.f);
            }
            if (RESID) {
                float4 rv = *reinterpret_cast<const float4*>(resid + (size_t)r * N + cn);
                o.x += rv.x; o.y += rv.y; o.z += rv.z; o.w += rv.w;
            }
            *reinterpret_cast<float4*>(C + (size_t)r * N + cn) = o;
        }
    }
}

// ---------------------------------------------------------------------------
// fp32 flash attention. qkv layout: [B, L, 3, H, Dh] flat (row stride 3072).
// Block = one (b,h) x 32 q-rows; iterate 32 k-tiles of 64.
// Thread (ty,tx): 2 q-rows (ty*2+i), S-cols j*16+tx (bank-friendly), dh-cols tx*4+j.
// ---------------------------------------------------------------------------
__global__ __launch_bounds__(256)
void attn_kernel(const float* __restrict__ qkv, float* __restrict__ out)
{
    constexpr int ST = 68;           // padded row stride (floats)
    __shared__ float Qs[32 * ST];
    __shared__ float Ks[64 * ST];
    __shared__ float Vs[64 * ST];
    __shared__ float Ss[32 * ST];

    int bid = blockIdx.x;
    int qt = bid & 63;               // 64 q-tiles of 32 rows
    int bh = bid >> 6;
    int h = bh & 15, b = bh >> 4;
    int tid = threadIdx.x;
    int tx = tid & 15, ty = tid >> 4;
    const float* base = qkv + (size_t)b * L_SEQ * 3072 + h * 64;

    { // load Q tile: 32 rows x 64 (8 floats/thread)
        int lr = tid >> 3;           // 0..31
        int lc = (tid & 7) * 8;      // 0..56
        const float* qp = base + (size_t)(qt * 32 + lr) * 3072 + lc;
        *reinterpret_cast<float4*>(&Qs[lr * ST + lc])     = *reinterpret_cast<const float4*>(qp);
        *reinterpret_cast<float4*>(&Qs[lr * ST + lc + 4]) = *reinterpret_cast<const float4*>(qp + 4);
    }

    float m_[2] = {-INFINITY, -INFINITY};
    float l_[2] = {0.f, 0.f};
    float o_[2][4] = {{0.f,0.f,0.f,0.f},{0.f,0.f,0.f,0.f}};

    int kr = tid >> 2;               // 0..63
    int kc = (tid & 3) * 16;

    for (int kt = 0; kt < 32; ++kt) {
        __syncthreads();             // prev PV done before K/V overwrite
        const float* kp = base + 1024 + (size_t)(kt * 64 + kr) * 3072 + kc;
        const float* vp = base + 2048 + (size_t)(kt * 64 + kr) * 3072 + kc;
        #pragma unroll
        for (int cc = 0; cc < 16; cc += 4) {
            *reinterpret_cast<float4*>(&Ks[kr * ST + kc + cc]) = *reinterpret_cast<const float4*>(kp + cc);
            *reinterpret_cast<float4*>(&Vs[kr * ST + kc + cc]) = *reinterpret_cast<const float4*>(vp + cc);
        }
        __syncthreads();             // also covers Q tile on first iter

        // S = Q K^T  (thread's k-cols are j*16+tx)
        float s[2][4] = {{0.f,0.f,0.f,0.f},{0.f,0.f,0.f,0.f}};
        #pragma unroll
        for (int d = 0; d < 64; d += 4) {
            float4 q0 = *reinterpret_cast<const float4*>(&Qs[(ty*2 + 0) * ST + d]);
            float4 q1 = *reinterpret_cast<const float4*>(&Qs[(ty*2 + 1) * ST + d]);
            #pragma unroll
            for (int j = 0; j < 4; ++j) {
                float4 k4 = *reinterpret_cast<const float4*>(&Ks[(j*16 + tx) * ST + d]);
                s[0][j] = fmaf(q0.x, k4.x, s[0][j]);
                s[0][j] = fmaf(q0.y, k4.y, s[0][j]);
                s[0][j] = fmaf(q0.z, k4.z, s[0][j]);
                s[0][j] = fmaf(q0.w, k4.w, s[0][j]);
                s[1][j] = fmaf(q1.x, k4.x, s[1][j]);
                s[1][j] = fmaf(q1.y, k4.y, s[1][j]);
                s[1][j] = fmaf(q1.z, k4.z, s[1][j]);
                s[1][j] = fmaf(q1.w, k4.w, s[1][j]);
            }
        }

        // online softmax update (rows reduce across the 16 tx lanes)
        #pragma unroll
        for (int i = 0; i < 2; ++i) {
            float sv[4];
            #pragma unroll
            for (int j = 0; j < 4; ++j) sv[j] = s[i][j] * 0.125f;  // Dh^-0.5
            float rm = fmaxf(fmaxf(sv[0], sv[1]), fmaxf(sv[2], sv[3]));
            rm = fmaxf(rm, __shfl_xor(rm, 1));
            rm = fmaxf(rm, __shfl_xor(rm, 2));
            rm = fmaxf(rm, __shfl_xor(rm, 4));
            rm = fmaxf(rm, __shfl_xor(rm, 8));
            float mn  = fmaxf(m_[i], rm);
            float fac = expf(m_[i] - mn);
            float p[4];
            float rs = 0.f;
            #pragma unroll
            for (int j = 0; j < 4; ++j) { p[j] = expf(sv[j] - mn); rs += p[j]; }
            rs += __shfl_xor(rs, 1);
            rs += __shfl_xor(rs, 2);
            rs += __shfl_xor(rs, 4);
            rs += __shfl_xor(rs, 8);
            l_[i] = l_[i] * fac + rs;
            m_[i] = mn;
            #pragma unroll
            for (int j = 0; j < 4; ++j) o_[i][j] *= fac;
            #pragma unroll
            for (int j = 0; j < 4; ++j) Ss[(ty*2 + i) * ST + j*16 + tx] = p[j];
        }
        __syncthreads();

        // O += P @ V   (thread's dh-cols are tx*4+j)
        #pragma unroll
        for (int kk = 0; kk < 64; kk += 4) {
            float4 p0 = *reinterpret_cast<const float4*>(&Ss[(ty*2 + 0) * ST + kk]);
            float4 p1 = *reinterpret_cast<const float4*>(&Ss[(ty*2 + 1) * ST + kk]);
            float va[4][4];
            #pragma unroll
            for (int c = 0; c < 4; ++c) {
                float4 t4 = *reinterpret_cast<const float4*>(&Vs[(kk + c) * ST + tx * 4]);
                va[c][0] = t4.x; va[c][1] = t4.y; va[c][2] = t4.z; va[c][3] = t4.w;
            }
            #pragma unroll
            for (int j = 0; j < 4; ++j) {
                o_[0][j] = fmaf(p0.x, va[0][j], o_[0][j]);
                o_[0][j] = fmaf(p0.y, va[1][j], o_[0][j]);
                o_[0][j] = fmaf(p0.z, va[2][j], o_[0][j]);
                o_[0][j] = fmaf(p0.w, va[3][j], o_[0][j]);
                o_[1][j] = fmaf(p1.x, va[0][j], o_[1][j]);
                o_[1][j] = fmaf(p1.y, va[1][j], o_[1][j]);
                o_[1][j] = fmaf(p1.z, va[2][j], o_[1][j]);
                o_[1][j] = fmaf(p1.w, va[3][j], o_[1][j]);
            }
        }
    }

    // epilogue: out[b*L + qt*32 + r, h*64 + tx*4 + j] = o/l
    float inv0 = 1.0f / l_[0];
    float inv1 = 1.0f / l_[1];
    float* op = out + ((size_t)(b * L_SEQ + qt * 32)) * D_MODEL + h * 64 + tx * 4;
    float4 r0 = {o_[0][0]*inv0, o_[0][1]*inv0, o_[0][2]*inv0, o_[0][3]*inv0};
    float4 r1 = {o_[1][0]*inv1, o_[1][1]*inv1, o_[1][2]*inv1, o_[1][3]*inv1};
    *reinterpret_cast<float4*>(op + (size_t)(ty*2 + 0) * D_MODEL) = r0;
    *reinterpret_cast<float4*>(op + (size_t)(ty*2 + 1) * D_MODEL) = r1;
}

// ---------------------------------------------------------------------------
extern "C" void kernel_launch(void* const* d_in, const int* in_sizes, int n_in,
                              void* d_out, int out_size, void* d_ws, size_t ws_size,
                              hipStream_t stream)
{
    const float* src    = (const float*)d_in[0];
    const float* w_qkv  = (const float*)d_in[1];
    const float* w_out  = (const float*)d_in[2];
    const float* b_out  = (const float*)d_in[3];
    const float* w1     = (const float*)d_in[4];
    const float* b1     = (const float*)d_in[5];
    const float* w2     = (const float*)d_in[6];
    const float* b2     = (const float*)d_in[7];
    const float* gamma1 = (const float*)d_in[8];
    const float* beta1  = (const float*)d_in[9];
    const float* gamma2 = (const float*)d_in[10];
    const float* beta2  = (const float*)d_in[11];
    float* out = (float*)d_out;

    // workspace layout (floats):
    //   [0 .. 25165824)              qkv  (8192x3072)   } reused as h1 (8192x4096)
    //   [25165824 .. 33554432)       attn_out (8192x1024)}   after attention phase
    //   [33554432 .. 41943040)       xnorm / x2 (8192x1024)
    // src2 lives in d_out.  Total: 160 MB.
    float* ws     = (float*)d_ws;
    float* qkv    = ws;
    float* attn_o = ws + (size_t)8192 * 3072;
    float* xnorm  = attn_o + (size_t)8192 * 1024;
    float* h1     = ws;   // reuses qkv + attn_o region

    dim3 blk(256);

    // 1. x_norm = LN(src)
    ln_kernel<<<M_ROWS, blk, 0, stream>>>(src, gamma1, beta1, xnorm);
    // 2. qkv = x_norm @ w_qkv
    gemm128<false,false,false><<<dim3(3072/128, 8192/128), blk, 0, stream>>>(
        xnorm, w_qkv, nullptr, nullptr, qkv, M_ROWS, 3072, 1024);
    // 3. attention
    attn_kernel<<<N_BATCH * N_HEAD * (L_SEQ/32), blk, 0, stream>>>(qkv, attn_o);
    // 4. src2 = src + attn_o @ w_out + b_out   -> d_out
    gemm128<true,false,true><<<dim3(1024/128, 8192/128), blk, 0, stream>>>(
        attn_o, w_out, b_out, src, out, M_ROWS, 1024, 1024);
    // 5. x2 = LN(src2)
    ln_kernel<<<M_ROWS, blk, 0, stream>>>(out, gamma2, beta2, xnorm);
    // 6. h1 = relu(x2 @ w1 + b1)
    gemm128<true,true,false><<<dim3(4096/128, 8192/128), blk, 0, stream>>>(
        xnorm, w1, b1, nullptr, h1, M_ROWS, 4096, 1024);
    // 7. out = src2 + h1 @ w2 + b2   (in-place residual from d_out)
    gemm128<true,false,true><<<dim3(1024/128, 8192/128), blk, 0, stream>>>(
        h1, w2, b2, out, out, M_ROWS, 1024, 4096);
}

// Round 2
// 1765.288 us; speedup vs baseline: 2.0385x; 2.0385x over previous
//
#include <hip/hip_runtime.h>
#include <cmath>

#define D_MODEL 1024
#define L_SEQ   2048
#define N_BATCH 4
#define N_HEAD  16
#define D_FF    4096
#define M_ROWS  (N_BATCH * L_SEQ)   // 8192

typedef _Float16 half8 __attribute__((ext_vector_type(8)));
typedef _Float16 half4 __attribute__((ext_vector_type(4)));
typedef float    f32x4 __attribute__((ext_vector_type(4)));

// ---------------------------------------------------------------------------
// async global->LDS 16B per lane (wave instruction). LDS dest must be
// wave-uniform base; HW writes base + lane*16. Generic->AS3 via low-32 bits
// (LDS aperture is 4GB-aligned, so low 32 bits of a generic LDS address are
// the LDS byte offset).
// ---------------------------------------------------------------------------
__device__ __forceinline__ void gload16(const void* g, const void* lds) {
    __builtin_amdgcn_global_load_lds(
        (__attribute__((address_space(1))) uint32_t*)(uintptr_t)g,
        (__attribute__((address_space(3))) uint32_t*)(uint32_t)(uintptr_t)lds,
        16, 0, 0);
}

// ---------------------------------------------------------------------------
// weight prep: in[K][N] fp32 -> out[N][K] fp16  (transpose + downconvert)
// grid: (N/32, K/32), 256 threads
// ---------------------------------------------------------------------------
__global__ __launch_bounds__(256)
void wprep_kernel(const float* __restrict__ in, _Float16* __restrict__ out,
                  int K, int N)
{
    __shared__ float tile[32][33];
    int tid = threadIdx.x;
    int tx = tid & 31, ty = tid >> 5;          // 32 x 8
    int n0 = blockIdx.x * 32, k0 = blockIdx.y * 32;
    #pragma unroll
    for (int r = 0; r < 4; ++r)
        tile[ty + 8*r][tx] = in[(size_t)(k0 + ty + 8*r) * N + (n0 + tx)];
    __syncthreads();
    #pragma unroll
    for (int r = 0; r < 4; ++r)
        out[(size_t)(n0 + ty + 8*r) * K + (k0 + tx)] = (_Float16)tile[tx][ty + 8*r];
}

// ---------------------------------------------------------------------------
// LayerNorm: fp32 in -> fp16 out. one block per row (D=1024), 256 thr * 4
// ---------------------------------------------------------------------------
__global__ __launch_bounds__(256)
void ln16_kernel(const float* __restrict__ x, const float* __restrict__ gamma,
                 const float* __restrict__ beta, _Float16* __restrict__ y)
{
    int row = blockIdx.x;
    int t = threadIdx.x;
    const float4* xr = reinterpret_cast<const float4*>(x + (size_t)row * D_MODEL);
    float4 v = xr[t];
    float s  = v.x + v.y + v.z + v.w;
    float s2 = v.x*v.x + v.y*v.y + v.z*v.z + v.w*v.w;
    #pragma unroll
    for (int off = 32; off > 0; off >>= 1) {
        s  += __shfl_down(s,  off);
        s2 += __shfl_down(s2, off);
    }
    __shared__ float red[8];
    int wid = t >> 6;
    if ((t & 63) == 0) { red[wid] = s; red[4 + wid] = s2; }
    __syncthreads();
    s  = red[0] + red[1] + red[2] + red[3];
    s2 = red[4] + red[5] + red[6] + red[7];
    float mu   = s * (1.0f / D_MODEL);
    float var  = s2 * (1.0f / D_MODEL) - mu * mu;
    float rstd = rsqrtf(var + 1e-5f);
    float4 g  = reinterpret_cast<const float4*>(gamma)[t];
    float4 bb = reinterpret_cast<const float4*>(beta)[t];
    half4 o;
    o[0] = (_Float16)((v.x - mu) * rstd * g.x + bb.x);
    o[1] = (_Float16)((v.y - mu) * rstd * g.y + bb.y);
    o[2] = (_Float16)((v.z - mu) * rstd * g.z + bb.z);
    o[3] = (_Float16)((v.w - mu) * rstd * g.w + bb.w);
    *reinterpret_cast<half4*>(y + (size_t)row * D_MODEL + t * 4) = o;
}

// ---------------------------------------------------------------------------
// fp16 MFMA GEMM: C[M,N] = A[M,K] @ Bt[N,K]^T, fp32 accumulate.
// 128x128 tile, BK=32, 4 waves (2x2 of 64x64), mfma_f32_16x16x32_f16.
// LDS [128][32] fp16 (64B rows): frag ds_read_b128 spread over 8 bank-quads
// -> conflict-free, and linear dest works with global_load_lds.
// Double-buffered, one barrier/K-step (compiler drains vmcnt+lgkm at barrier).
// ---------------------------------------------------------------------------
template<bool HAS_BIAS, bool RELU, bool RESID, bool OUT_HALF>
__global__ __launch_bounds__(256, 2)
void gemm_f16(const _Float16* __restrict__ A, const _Float16* __restrict__ Bt,
              const float* __restrict__ bias, const float* __restrict__ resid,
              float* __restrict__ outF, _Float16* __restrict__ outH,
              int M, int N, int K)
{
    __shared__ _Float16 As[2][128][32];
    __shared__ _Float16 Bs[2][128][32];

    // XCD-aware bijective swizzle (grid counts are all % 8 == 0)
    int nwg = gridDim.x;
    int bid = blockIdx.x;
    int cpx = nwg >> 3;
    int swz = (bid & 7) * cpx + (bid >> 3);
    int nbn = N >> 7;
    int bm0 = (swz / nbn) << 7;
    int bn0 = (swz % nbn) << 7;

    int tid = threadIdx.x;
    int wv = tid >> 6, ln = tid & 63;
    int wm = (wv >> 1) * 64, wn = (wv & 1) * 64;
    int lr = ln & 15, kg = ln >> 4;

    // staging source rows for this lane (16B per lane per call)
    int srow = (ln >> 2);            // 0..15
    int scol = (ln & 3) * 8;         // halfs within 32-k row

    const _Float16* gA = A  + (size_t)(bm0 + wv*32 + srow) * K + scol;
    const _Float16* gB = Bt + (size_t)(bn0 + wv*32 + srow) * K + scol;

    f32x4 acc[4][4] = {};

    const int NK = K >> 5;

    // prologue: stage tile 0 into buf 0
    {
        gload16(gA,                  &As[0][wv*32     ][0]);
        gload16(gA + (size_t)16 * K, &As[0][wv*32 + 16][0]);
        gload16(gB,                  &Bs[0][wv*32     ][0]);
        gload16(gB + (size_t)16 * K, &Bs[0][wv*32 + 16][0]);
    }

    int cur = 0;
    for (int kt = 0; kt < NK; ++kt) {
        __syncthreads();   // drains vmcnt -> staged buf 'cur' visible to all
        if (kt + 1 < NK) {
            const _Float16* nA = gA + (size_t)(kt + 1) * 32;
            const _Float16* nB = gB + (size_t)(kt + 1) * 32;
            int nb = cur ^ 1;
            gload16(nA,                  &As[nb][wv*32     ][0]);
            gload16(nA + (size_t)16 * K, &As[nb][wv*32 + 16][0]);
            gload16(nB,                  &Bs[nb][wv*32     ][0]);
            gload16(nB + (size_t)16 * K, &Bs[nb][wv*32 + 16][0]);
        }
        half8 af[4], bf[4];
        #pragma unroll
        for (int f = 0; f < 4; ++f)
            af[f] = *reinterpret_cast<const half8*>(&As[cur][wm + f*16 + lr][kg * 8]);
        #pragma unroll
        for (int f = 0; f < 4; ++f)
            bf[f] = *reinterpret_cast<const half8*>(&Bs[cur][wn + f*16 + lr][kg * 8]);
        #pragma unroll
        for (int i = 0; i < 4; ++i)
            #pragma unroll
            for (int j = 0; j < 4; ++j)
                acc[i][j] = __builtin_amdgcn_mfma_f32_16x16x32_f16(af[i], bf[j], acc[i][j], 0, 0, 0);
        cur ^= 1;
    }

    // epilogue: C/D layout col = lane&15, row = (lane>>4)*4 + reg   [m89]
    #pragma unroll
    for (int i = 0; i < 4; ++i) {
        int rbase = bm0 + wm + i*16 + kg*4;
        #pragma unroll
        for (int j = 0; j < 4; ++j) {
            int c = bn0 + wn + j*16 + lr;
            float bi = 0.0f;
            if (HAS_BIAS) bi = bias[c];
            #pragma unroll
            for (int reg = 0; reg < 4; ++reg) {
                size_t idx = (size_t)(rbase + reg) * N + c;
                float v = acc[i][j][reg] + bi;
                if (RELU)  v = fmaxf(v, 0.0f);
                if (RESID) v += resid[idx];
                if constexpr (OUT_HALF) outH[idx] = (_Float16)v;
                else                    outF[idx] = v;
            }
        }
    }
}

// ---------------------------------------------------------------------------
// fp32 flash attention (unchanged math; epilogue now writes fp16).
// qkv layout: [B, L, 3, H, Dh] flat (row stride 3072).
// ---------------------------------------------------------------------------
__global__ __launch_bounds__(256)
void attn_kernel(const float* __restrict__ qkv, _Float16* __restrict__ out)
{
    constexpr int ST = 68;
    __shared__ float Qs[32 * ST];
    __shared__ float Ks[64 * ST];
    __shared__ float Vs[64 * ST];
    __shared__ float Ss[32 * ST];

    int bid = blockIdx.x;
    int qt = bid & 63;
    int bh = bid >> 6;
    int h = bh & 15, b = bh >> 4;
    int tid = threadIdx.x;
    int tx = tid & 15, ty = tid >> 4;
    const float* base = qkv + (size_t)b * L_SEQ * 3072 + h * 64;

    {
        int lr = tid >> 3;
        int lc = (tid & 7) * 8;
        const float* qp = base + (size_t)(qt * 32 + lr) * 3072 + lc;
        *reinterpret_cast<float4*>(&Qs[lr * ST + lc])     = *reinterpret_cast<const float4*>(qp);
        *reinterpret_cast<float4*>(&Qs[lr * ST + lc + 4]) = *reinterpret_cast<const float4*>(qp + 4);
    }

    float m_[2] = {-INFINITY, -INFINITY};
    float l_[2] = {0.f, 0.f};
    float o_[2][4] = {{0.f,0.f,0.f,0.f},{0.f,0.f,0.f,0.f}};

    int kr = tid >> 2;
    int kc = (tid & 3) * 16;

    for (int kt = 0; kt < 32; ++kt) {
        __syncthreads();
        const float* kp = base + 1024 + (size_t)(kt * 64 + kr) * 3072 + kc;
        const float* vp = base + 2048 + (size_t)(kt * 64 + kr) * 3072 + kc;
        #pragma unroll
        for (int cc = 0; cc < 16; cc += 4) {
            *reinterpret_cast<float4*>(&Ks[kr * ST + kc + cc]) = *reinterpret_cast<const float4*>(kp + cc);
            *reinterpret_cast<float4*>(&Vs[kr * ST + kc + cc]) = *reinterpret_cast<const float4*>(vp + cc);
        }
        __syncthreads();

        float s[2][4] = {{0.f,0.f,0.f,0.f},{0.f,0.f,0.f,0.f}};
        #pragma unroll
        for (int d = 0; d < 64; d += 4) {
            float4 q0 = *reinterpret_cast<const float4*>(&Qs[(ty*2 + 0) * ST + d]);
            float4 q1 = *reinterpret_cast<const float4*>(&Qs[(ty*2 + 1) * ST + d]);
            #pragma unroll
            for (int j = 0; j < 4; ++j) {
                float4 k4 = *reinterpret_cast<const float4*>(&Ks[(j*16 + tx) * ST + d]);
                s[0][j] = fmaf(q0.x, k4.x, s[0][j]);
                s[0][j] = fmaf(q0.y, k4.y, s[0][j]);
                s[0][j] = fmaf(q0.z, k4.z, s[0][j]);
                s[0][j] = fmaf(q0.w, k4.w, s[0][j]);
                s[1][j] = fmaf(q1.x, k4.x, s[1][j]);
                s[1][j] = fmaf(q1.y, k4.y, s[1][j]);
                s[1][j] = fmaf(q1.z, k4.z, s[1][j]);
                s[1][j] = fmaf(q1.w, k4.w, s[1][j]);
            }
        }

        #pragma unroll
        for (int i = 0; i < 2; ++i) {
            float sv[4];
            #pragma unroll
            for (int j = 0; j < 4; ++j) sv[j] = s[i][j] * 0.125f;
            float rm = fmaxf(fmaxf(sv[0], sv[1]), fmaxf(sv[2], sv[3]));
            rm = fmaxf(rm, __shfl_xor(rm, 1));
            rm = fmaxf(rm, __shfl_xor(rm, 2));
            rm = fmaxf(rm, __shfl_xor(rm, 4));
            rm = fmaxf(rm, __shfl_xor(rm, 8));
            float mn  = fmaxf(m_[i], rm);
            float fac = expf(m_[i] - mn);
            float p[4];
            float rs = 0.f;
            #pragma unroll
            for (int j = 0; j < 4; ++j) { p[j] = expf(sv[j] - mn); rs += p[j]; }
            rs += __shfl_xor(rs, 1);
            rs += __shfl_xor(rs, 2);
            rs += __shfl_xor(rs, 4);
            rs += __shfl_xor(rs, 8);
            l_[i] = l_[i] * fac + rs;
            m_[i] = mn;
            #pragma unroll
            for (int j = 0; j < 4; ++j) o_[i][j] *= fac;
            #pragma unroll
            for (int j = 0; j < 4; ++j) Ss[(ty*2 + i) * ST + j*16 + tx] = p[j];
        }
        __syncthreads();

        #pragma unroll
        for (int kk = 0; kk < 64; kk += 4) {
            float4 p0 = *reinterpret_cast<const float4*>(&Ss[(ty*2 + 0) * ST + kk]);
            float4 p1 = *reinterpret_cast<const float4*>(&Ss[(ty*2 + 1) * ST + kk]);
            float va[4][4];
            #pragma unroll
            for (int c = 0; c < 4; ++c) {
                float4 t4 = *reinterpret_cast<const float4*>(&Vs[(kk + c) * ST + tx * 4]);
                va[c][0] = t4.x; va[c][1] = t4.y; va[c][2] = t4.z; va[c][3] = t4.w;
            }
            #pragma unroll
            for (int j = 0; j < 4; ++j) {
                o_[0][j] = fmaf(p0.x, va[0][j], o_[0][j]);
                o_[0][j] = fmaf(p0.y, va[1][j], o_[0][j]);
                o_[0][j] = fmaf(p0.z, va[2][j], o_[0][j]);
                o_[0][j] = fmaf(p0.w, va[3][j], o_[0][j]);
                o_[1][j] = fmaf(p1.x, va[0][j], o_[1][j]);
                o_[1][j] = fmaf(p1.y, va[1][j], o_[1][j]);
                o_[1][j] = fmaf(p1.z, va[2][j], o_[1][j]);
                o_[1][j] = fmaf(p1.w, va[3][j], o_[1][j]);
            }
        }
    }

    float inv0 = 1.0f / l_[0];
    float inv1 = 1.0f / l_[1];
    _Float16* op = out + ((size_t)(b * L_SEQ + qt * 32)) * D_MODEL + h * 64 + tx * 4;
    half4 r0, r1;
    #pragma unroll
    for (int j = 0; j < 4; ++j) {
        r0[j] = (_Float16)(o_[0][j] * inv0);
        r1[j] = (_Float16)(o_[1][j] * inv1);
    }
    *reinterpret_cast<half4*>(op + (size_t)(ty*2 + 0) * D_MODEL) = r0;
    *reinterpret_cast<half4*>(op + (size_t)(ty*2 + 1) * D_MODEL) = r1;
}

// ---------------------------------------------------------------------------
extern "C" void kernel_launch(void* const* d_in, const int* in_sizes, int n_in,
                              void* d_out, int out_size, void* d_ws, size_t ws_size,
                              hipStream_t stream)
{
    const float* src    = (const float*)d_in[0];
    const float* w_qkv  = (const float*)d_in[1];
    const float* w_out  = (const float*)d_in[2];
    const float* b_out  = (const float*)d_in[3];
    const float* w1     = (const float*)d_in[4];
    const float* b1     = (const float*)d_in[5];
    const float* w2     = (const float*)d_in[6];
    const float* b2     = (const float*)d_in[7];
    const float* gamma1 = (const float*)d_in[8];
    const float* beta1  = (const float*)d_in[9];
    const float* gamma2 = (const float*)d_in[10];
    const float* beta2  = (const float*)d_in[11];
    float* out = (float*)d_out;

    // workspace layout (bytes):
    //   [0,          100663296)  qkv fp32 [8192][3072]  -> reused as h1 f16 [8192][4096] (64MB)
    //   [100663296,  106954752)  w_qkvT f16 [3072][1024]
    //   [106954752,  109051904)  w_outT f16 [1024][1024]
    //   [109051904,  117440512)  w1T    f16 [4096][1024]
    //   [117440512,  125829120)  w2T    f16 [1024][4096]
    //   [125829120,  142606336)  xnorm/x2 f16 [8192][1024]
    //   [142606336,  159383552)  attn_o  f16 [8192][1024]
    char* w = (char*)d_ws;
    float*    qkv  = (float*)(w + 0);
    _Float16* h1   = (_Float16*)(w + 0);
    _Float16* wqT  = (_Float16*)(w + 100663296);
    _Float16* woT  = (_Float16*)(w + 106954752);
    _Float16* w1T  = (_Float16*)(w + 109051904);
    _Float16* w2T  = (_Float16*)(w + 117440512);
    _Float16* xn   = (_Float16*)(w + 125829120);
    _Float16* ao   = (_Float16*)(w + 142606336);

    dim3 blk(256);

    // weight prep (transpose + fp16)
    wprep_kernel<<<dim3(3072/32, 1024/32), blk, 0, stream>>>(w_qkv, wqT, 1024, 3072);
    wprep_kernel<<<dim3(1024/32, 1024/32), blk, 0, stream>>>(w_out, woT, 1024, 1024);
    wprep_kernel<<<dim3(4096/32, 1024/32), blk, 0, stream>>>(w1,    w1T, 1024, 4096);
    wprep_kernel<<<dim3(1024/32, 4096/32), blk, 0, stream>>>(w2,    w2T, 4096, 1024);

    // 1. xnorm = LN(src)  (fp16 out)
    ln16_kernel<<<M_ROWS, blk, 0, stream>>>(src, gamma1, beta1, xn);
    // 2. qkv = xnorm @ w_qkv  (fp32 out for fp32 attention)
    gemm_f16<false,false,false,false><<<(M_ROWS/128)*(3072/128), blk, 0, stream>>>(
        xn, wqT, nullptr, nullptr, qkv, nullptr, M_ROWS, 3072, 1024);
    // 3. attention -> fp16
    attn_kernel<<<N_BATCH * N_HEAD * (L_SEQ/32), blk, 0, stream>>>(qkv, ao);
    // 4. src2 = src + ao @ w_out + b_out  -> d_out (fp32)
    gemm_f16<true,false,true,false><<<(M_ROWS/128)*(1024/128), blk, 0, stream>>>(
        ao, woT, b_out, src, out, nullptr, M_ROWS, 1024, 1024);
    // 5. x2 = LN(src2) (fp16 out)
    ln16_kernel<<<M_ROWS, blk, 0, stream>>>(out, gamma2, beta2, xn);
    // 6. h1 = relu(x2 @ w1 + b1)  (fp16 out)
    gemm_f16<true,true,false,true><<<(M_ROWS/128)*(4096/128), blk, 0, stream>>>(
        xn, w1T, b1, nullptr, nullptr, h1, M_ROWS, 4096, 1024);
    // 7. out = src2 + h1 @ w2 + b2  (fp32, in-place residual from d_out)
    gemm_f16<true,false,true,false><<<(M_ROWS/128)*(1024/128), blk, 0, stream>>>(
        h1, w2T, b2, out, out, nullptr, M_ROWS, 1024, 4096);
}

// Round 5
// 571.371 us; speedup vs baseline: 6.2979x; 3.0896x over previous
//
#include <hip/hip_runtime.h>
#include <cmath>

#define D_MODEL 1024
#define L_SEQ   2048
#define N_BATCH 4
#define N_HEAD  16
#define D_FF    4096
#define M_ROWS  (N_BATCH * L_SEQ)   // 8192

typedef _Float16 half8 __attribute__((ext_vector_type(8)));
typedef _Float16 half4 __attribute__((ext_vector_type(4)));
typedef float    f32x4 __attribute__((ext_vector_type(4)));

// ---------------------------------------------------------------------------
// async global->LDS 16B per lane (used ONLY by the validated GEMM).
// ---------------------------------------------------------------------------
__device__ __forceinline__ void gload16(const void* g, const void* lds) {
    __builtin_amdgcn_global_load_lds(
        (__attribute__((address_space(1))) uint32_t*)(uintptr_t)g,
        (__attribute__((address_space(3))) uint32_t*)(uint32_t)(uintptr_t)lds,
        16, 0, 0);
}

// ---------------------------------------------------------------------------
// weight prep: in[K][N] fp32 -> out[N][K] fp16  (transpose + downconvert)
// ---------------------------------------------------------------------------
__global__ __launch_bounds__(256)
void wprep_kernel(const float* __restrict__ in, _Float16* __restrict__ out,
                  int K, int N)
{
    __shared__ float tile[32][33];
    int tid = threadIdx.x;
    int tx = tid & 31, ty = tid >> 5;
    int n0 = blockIdx.x * 32, k0 = blockIdx.y * 32;
    #pragma unroll
    for (int r = 0; r < 4; ++r)
        tile[ty + 8*r][tx] = in[(size_t)(k0 + ty + 8*r) * N + (n0 + tx)];
    __syncthreads();
    #pragma unroll
    for (int r = 0; r < 4; ++r)
        out[(size_t)(n0 + ty + 8*r) * K + (k0 + tx)] = (_Float16)tile[tx][ty + 8*r];
}

// ---------------------------------------------------------------------------
// LayerNorm: fp32 in -> fp16 out
// ---------------------------------------------------------------------------
__global__ __launch_bounds__(256)
void ln16_kernel(const float* __restrict__ x, const float* __restrict__ gamma,
                 const float* __restrict__ beta, _Float16* __restrict__ y)
{
    int row = blockIdx.x;
    int t = threadIdx.x;
    const float4* xr = reinterpret_cast<const float4*>(x + (size_t)row * D_MODEL);
    float4 v = xr[t];
    float s  = v.x + v.y + v.z + v.w;
    float s2 = v.x*v.x + v.y*v.y + v.z*v.z + v.w*v.w;
    #pragma unroll
    for (int off = 32; off > 0; off >>= 1) {
        s  += __shfl_down(s,  off);
        s2 += __shfl_down(s2, off);
    }
    __shared__ float red[8];
    int wid = t >> 6;
    if ((t & 63) == 0) { red[wid] = s; red[4 + wid] = s2; }
    __syncthreads();
    s  = red[0] + red[1] + red[2] + red[3];
    s2 = red[4] + red[5] + red[6] + red[7];
    float mu   = s * (1.0f / D_MODEL);
    float var  = s2 * (1.0f / D_MODEL) - mu * mu;
    float rstd = rsqrtf(var + 1e-5f);
    float4 g  = reinterpret_cast<const float4*>(gamma)[t];
    float4 bb = reinterpret_cast<const float4*>(beta)[t];
    half4 o;
    o[0] = (_Float16)((v.x - mu) * rstd * g.x + bb.x);
    o[1] = (_Float16)((v.y - mu) * rstd * g.y + bb.y);
    o[2] = (_Float16)((v.z - mu) * rstd * g.z + bb.z);
    o[3] = (_Float16)((v.w - mu) * rstd * g.w + bb.w);
    *reinterpret_cast<half4*>(y + (size_t)row * D_MODEL + t * 4) = o;
}

// ---------------------------------------------------------------------------
// fp16 MFMA GEMM: C = A @ Bt^T, fp32 accumulate. (validated round 2, unchanged)
// ---------------------------------------------------------------------------
template<bool HAS_BIAS, bool RELU, bool RESID, bool OUT_HALF>
__global__ __launch_bounds__(256, 2)
void gemm_f16(const _Float16* __restrict__ A, const _Float16* __restrict__ Bt,
              const float* __restrict__ bias, const float* __restrict__ resid,
              float* __restrict__ outF, _Float16* __restrict__ outH,
              int M, int N, int K)
{
    __shared__ _Float16 As[2][128][32];
    __shared__ _Float16 Bs[2][128][32];

    int nwg = gridDim.x;
    int bid = blockIdx.x;
    int cpx = nwg >> 3;
    int swz = (bid & 7) * cpx + (bid >> 3);
    int nbn = N >> 7;
    int bm0 = (swz / nbn) << 7;
    int bn0 = (swz % nbn) << 7;

    int tid = threadIdx.x;
    int wv = tid >> 6, ln = tid & 63;
    int wm = (wv >> 1) * 64, wn = (wv & 1) * 64;
    int lr = ln & 15, kg = ln >> 4;

    int srow = (ln >> 2);
    int scol = (ln & 3) * 8;

    const _Float16* gA = A  + (size_t)(bm0 + wv*32 + srow) * K + scol;
    const _Float16* gB = Bt + (size_t)(bn0 + wv*32 + srow) * K + scol;

    f32x4 acc[4][4] = {};
    const int NK = K >> 5;

    {
        gload16(gA,                  &As[0][wv*32     ][0]);
        gload16(gA + (size_t)16 * K, &As[0][wv*32 + 16][0]);
        gload16(gB,                  &Bs[0][wv*32     ][0]);
        gload16(gB + (size_t)16 * K, &Bs[0][wv*32 + 16][0]);
    }

    int cur = 0;
    for (int kt = 0; kt < NK; ++kt) {
        __syncthreads();
        if (kt + 1 < NK) {
            const _Float16* nA = gA + (size_t)(kt + 1) * 32;
            const _Float16* nB = gB + (size_t)(kt + 1) * 32;
            int nb = cur ^ 1;
            gload16(nA,                  &As[nb][wv*32     ][0]);
            gload16(nA + (size_t)16 * K, &As[nb][wv*32 + 16][0]);
            gload16(nB,                  &Bs[nb][wv*32     ][0]);
            gload16(nB + (size_t)16 * K, &Bs[nb][wv*32 + 16][0]);
        }
        half8 af[4], bf[4];
        #pragma unroll
        for (int f = 0; f < 4; ++f)
            af[f] = *reinterpret_cast<const half8*>(&As[cur][wm + f*16 + lr][kg * 8]);
        #pragma unroll
        for (int f = 0; f < 4; ++f)
            bf[f] = *reinterpret_cast<const half8*>(&Bs[cur][wn + f*16 + lr][kg * 8]);
        #pragma unroll
        for (int i = 0; i < 4; ++i)
            #pragma unroll
            for (int j = 0; j < 4; ++j)
                acc[i][j] = __builtin_amdgcn_mfma_f32_16x16x32_f16(af[i], bf[j], acc[i][j], 0, 0, 0);
        cur ^= 1;
    }

    #pragma unroll
    for (int i = 0; i < 4; ++i) {
        int rbase = bm0 + wm + i*16 + kg*4;
        #pragma unroll
        for (int j = 0; j < 4; ++j) {
            int c = bn0 + wn + j*16 + lr;
            float bi = 0.0f;
            if (HAS_BIAS) bi = bias[c];
            #pragma unroll
            for (int reg = 0; reg < 4; ++reg) {
                size_t idx = (size_t)(rbase + reg) * N + c;
                float v = acc[i][j][reg] + bi;
                if (RELU)  v = fmaxf(v, 0.0f);
                if (RESID) v += resid[idx];
                if constexpr (OUT_HALF) outH[idx] = (_Float16)v;
                else                    outF[idx] = v;
            }
        }
    }
}

// ---------------------------------------------------------------------------
// V repack v2 (no LDS, trivially correct):
// Vt[(bh*64 + d)][l] = qkv16[(b*L + l)*3072 + 2048 + h*64 + d]
// grid (64 bh, 64 token-groups), 256 thr: lane d = t&63, 8 tokens per thread.
// ---------------------------------------------------------------------------
__global__ __launch_bounds__(256)
void vrepack_kernel(const _Float16* __restrict__ qkv16, _Float16* __restrict__ Vt)
{
    int bh = blockIdx.x;
    int b = bh >> 4, h = bh & 15;
    int t = threadIdx.x;
    int d = t & 63;
    int tok0 = blockIdx.y * 32 + (t >> 6) * 8;
    const _Float16* src = qkv16 + (size_t)(b * L_SEQ + tok0) * 3072 + 2048 + h * 64 + d;
    half8 v;
    #pragma unroll
    for (int j = 0; j < 8; ++j) v[j] = src[(size_t)j * 3072];
    *reinterpret_cast<half8*>(Vt + (size_t)(bh * 64 + d) * L_SEQ + tok0) = v;
}

// ---------------------------------------------------------------------------
// fp16 MFMA flash attention v2: swapped QK^T, padded LDS (72-half rows),
// register-staged K/V (issue-early / write-late), double-buffered, 1 barrier/tile.
// No swizzles, no global_load_lds.
// ---------------------------------------------------------------------------
__global__ __launch_bounds__(256, 2)
void fattn_kernel(const _Float16* __restrict__ qkv16, const _Float16* __restrict__ Vt,
                  _Float16* __restrict__ out)
{
    __shared__ _Float16 Ks[2][64][72];
    __shared__ _Float16 Vs[2][64][72];
    __shared__ _Float16 Ps[128][72];     // Q staging -> P tiles -> O bounce
    __shared__ float    fac_lds[4][32];

    int p = blockIdx.x;
    int logical = (p & 7) * 128 + (p >> 3);   // XCD-chunked, bijective (1024 % 8 == 0)
    int bh = logical >> 4;
    int qt = logical & 15;
    int b = bh >> 4, h = bh & 15;

    int tid = threadIdx.x;
    int w = tid >> 6, ln = tid & 63;
    int lr = ln & 15, lg = ln >> 4;

    char* psb = (char*)&Ps[0][0];
    const _Float16* qbase = qkv16 + (size_t)(b*L_SEQ + qt*128) * 3072 + h*64;
    const _Float16* kbase = qkv16 + (size_t)(b*L_SEQ) * 3072 + 1024 + h*64;
    const _Float16* vbase = Vt + (size_t)(bh*64) * L_SEQ;

    // staging assignments
    int qrow  = tid >> 1;            // 0..127 (wave w covers its own 32-row band)
    int qc    = (tid & 1) * 32;      // half offset
    int kvrow = tid >> 2;            // 0..63
    int kvc   = (tid & 3) * 8;       // chunks kvc and kvc+32

    // ---- prologue: stage Q + K/V tile 0 (reg-staged, plain ds writes) ----
    {
        half8 qv[4];
        #pragma unroll
        for (int j = 0; j < 4; ++j)
            qv[j] = *reinterpret_cast<const half8*>(qbase + (size_t)qrow * 3072 + qc + j*8);
        half8 kv0 = *reinterpret_cast<const half8*>(kbase + (size_t)kvrow * 3072 + kvc);
        half8 kv1 = *reinterpret_cast<const half8*>(kbase + (size_t)kvrow * 3072 + kvc + 32);
        half8 vv0 = *reinterpret_cast<const half8*>(vbase + (size_t)kvrow * L_SEQ + kvc);
        half8 vv1 = *reinterpret_cast<const half8*>(vbase + (size_t)kvrow * L_SEQ + kvc + 32);
        #pragma unroll
        for (int j = 0; j < 4; ++j)
            *reinterpret_cast<half8*>(&Ps[qrow][qc + j*8]) = qv[j];
        *reinterpret_cast<half8*>(&Ks[0][kvrow][kvc])      = kv0;
        *reinterpret_cast<half8*>(&Ks[0][kvrow][kvc + 32]) = kv1;
        *reinterpret_cast<half8*>(&Vs[0][kvrow][kvc])      = vv0;
        *reinterpret_cast<half8*>(&Vs[0][kvrow][kvc + 32]) = vv1;
    }
    __syncthreads();

    // ---- Q fragments (persistent): q = w*32 + nj*16 + lr, dh = (ks*4+lg)*8..+8
    half8 qf[2][2];
    #pragma unroll
    for (int nj = 0; nj < 2; ++nj)
        #pragma unroll
        for (int ks = 0; ks < 2; ++ks) {
            int q = w*32 + nj*16 + lr;
            qf[nj][ks] = *reinterpret_cast<const half8*>(psb + q*144 + (ks*4 + lg)*16);
        }

    float m_[2] = {-INFINITY, -INFINITY};
    float l_[2] = {0.f, 0.f};
    f32x4 oacc[2][4] = {};

    int cur = 0;
    for (int kt = 0; kt < 32; ++kt) {
        // issue next-tile global loads early (latency hides under compute)
        half8 kv0, kv1, vv0, vv1;
        const bool has_next = (kt + 1 < 32);
        if (has_next) {
            const _Float16* kp = kbase + (size_t)((kt+1)*64 + kvrow) * 3072;
            const _Float16* vp = vbase + (size_t)kvrow * L_SEQ + (kt+1)*64;
            kv0 = *reinterpret_cast<const half8*>(kp + kvc);
            kv1 = *reinterpret_cast<const half8*>(kp + kvc + 32);
            vv0 = *reinterpret_cast<const half8*>(vp + kvc);
            vv1 = *reinterpret_cast<const half8*>(vp + kvc + 32);
        }

        // ---- S^T = K @ Q^T : D[key = mi*16 + lg*4 + r][q = nj*16 + lr] ----
        const char* ksb = (const char*)&Ks[cur][0][0];
        f32x4 sacc[4][2] = {};
        #pragma unroll
        for (int mi = 0; mi < 4; ++mi) {
            half8 kf[2];
            #pragma unroll
            for (int ks = 0; ks < 2; ++ks)
                kf[ks] = *reinterpret_cast<const half8*>(ksb + (mi*16 + lr)*144 + (ks*4 + lg)*16);
            #pragma unroll
            for (int nj = 0; nj < 2; ++nj)
                #pragma unroll
                for (int ks = 0; ks < 2; ++ks)
                    sacc[mi][nj] = __builtin_amdgcn_mfma_f32_16x16x32_f16(kf[ks], qf[nj][ks], sacc[mi][nj], 0, 0, 0);
        }

        // ---- online softmax (q = w*32 + nj*16 + lr; keys on mi, lg, r) ----
        #pragma unroll
        for (int nj = 0; nj < 2; ++nj) {
            float sv[4][4];
            float pm = -3.4e38f;
            #pragma unroll
            for (int mi = 0; mi < 4; ++mi)
                #pragma unroll
                for (int r = 0; r < 4; ++r) {
                    sv[mi][r] = sacc[mi][nj][r] * 0.125f;
                    pm = fmaxf(pm, sv[mi][r]);
                }
            pm = fmaxf(pm, __shfl_xor(pm, 16));
            pm = fmaxf(pm, __shfl_xor(pm, 32));
            float mn  = fmaxf(m_[nj], pm);
            float fac = __expf(m_[nj] - mn);
            float rs = 0.f;
            half4 pk[4];
            #pragma unroll
            for (int mi = 0; mi < 4; ++mi)
                #pragma unroll
                for (int r = 0; r < 4; ++r) {
                    float pe = __expf(sv[mi][r] - mn);
                    rs += pe;
                    pk[mi][r] = (_Float16)pe;
                }
            rs += __shfl_xor(rs, 16);
            rs += __shfl_xor(rs, 32);
            l_[nj] = l_[nj] * fac + rs;
            m_[nj] = mn;
            if (lg == 0) fac_lds[w][nj*16 + lr] = fac;
            // P store: Ps[q][key = mi*16 + lg*4 .. +4]
            int q = w*32 + nj*16 + lr;
            #pragma unroll
            for (int mi = 0; mi < 4; ++mi)
                *reinterpret_cast<half4*>(psb + q*144 + mi*32 + lg*8) = pk[mi];
        }

        // ---- rescale O by fac (redistributed: q = i*16 + lg*4 + r) ----
        f32x4 facv[2];
        #pragma unroll
        for (int i = 0; i < 2; ++i)
            facv[i] = *reinterpret_cast<const f32x4*>(&fac_lds[w][i*16 + lg*4]);
        #pragma unroll
        for (int i = 0; i < 2; ++i)
            #pragma unroll
            for (int j = 0; j < 4; ++j)
                #pragma unroll
                for (int r = 0; r < 4; ++r)
                    oacc[i][j][r] *= facv[i][r];

        // ---- O += P @ V : D[q = i*16 + lg*4 + r][d = j*16 + lr] ----
        const char* vsb = (const char*)&Vs[cur][0][0];
        #pragma unroll
        for (int kc = 0; kc < 2; ++kc) {
            half8 pf[2], vf[4];
            #pragma unroll
            for (int i = 0; i < 2; ++i) {
                int q = w*32 + i*16 + lr;
                pf[i] = *reinterpret_cast<const half8*>(psb + q*144 + (kc*4 + lg)*16);
            }
            #pragma unroll
            for (int j = 0; j < 4; ++j) {
                int d = j*16 + lr;
                vf[j] = *reinterpret_cast<const half8*>(vsb + d*144 + (kc*4 + lg)*16);
            }
            #pragma unroll
            for (int i = 0; i < 2; ++i)
                #pragma unroll
                for (int j = 0; j < 4; ++j)
                    oacc[i][j] = __builtin_amdgcn_mfma_f32_16x16x32_f16(pf[i], vf[j], oacc[i][j], 0, 0, 0);
        }

        // ---- write staged K/V for tile kt+1 into the other buffer ----
        if (has_next) {
            int nb = cur ^ 1;
            *reinterpret_cast<half8*>(&Ks[nb][kvrow][kvc])      = kv0;
            *reinterpret_cast<half8*>(&Ks[nb][kvrow][kvc + 32]) = kv1;
            *reinterpret_cast<half8*>(&Vs[nb][kvrow][kvc])      = vv0;
            *reinterpret_cast<half8*>(&Vs[nb][kvrow][kvc + 32]) = vv1;
        }
        __syncthreads();
        cur ^= 1;
    }

    // ---- epilogue: O / l, bounce through Ps for coalesced stores ----
    if (lg == 0) {
        fac_lds[w][lr]      = l_[0];
        fac_lds[w][16 + lr] = l_[1];
    }
    f32x4 lv[2];
    #pragma unroll
    for (int i = 0; i < 2; ++i)
        lv[i] = *reinterpret_cast<const f32x4*>(&fac_lds[w][i*16 + lg*4]);
    #pragma unroll
    for (int i = 0; i < 2; ++i) {
        f32x4 inv;
        #pragma unroll
        for (int r = 0; r < 4; ++r) inv[r] = 1.0f / lv[i][r];
        #pragma unroll
        for (int j = 0; j < 4; ++j) {
            int d = j*16 + lr;
            #pragma unroll
            for (int r = 0; r < 4; ++r) {
                int q = w*32 + i*16 + lg*4 + r;
                *reinterpret_cast<_Float16*>(psb + q*144 + d*2)
                    = (_Float16)(oacc[i][j][r] * inv[r]);
            }
        }
    }
    #pragma unroll
    for (int it = 0; it < 4; ++it) {
        int r = it*8 + (ln >> 3);
        int s = ln & 7;
        int q = w*32 + r;
        half8 ov = *reinterpret_cast<const half8*>(psb + q*144 + s*16);
        size_t token = (size_t)(b*L_SEQ + qt*128 + q);
        *reinterpret_cast<half8*>(out + token*D_MODEL + h*64 + s*8) = ov;
    }
}

// ---------------------------------------------------------------------------
extern "C" void kernel_launch(void* const* d_in, const int* in_sizes, int n_in,
                              void* d_out, int out_size, void* d_ws, size_t ws_size,
                              hipStream_t stream)
{
    const float* src    = (const float*)d_in[0];
    const float* w_qkv  = (const float*)d_in[1];
    const float* w_out  = (const float*)d_in[2];
    const float* b_out  = (const float*)d_in[3];
    const float* w1     = (const float*)d_in[4];
    const float* b1     = (const float*)d_in[5];
    const float* w2     = (const float*)d_in[6];
    const float* b2     = (const float*)d_in[7];
    const float* gamma1 = (const float*)d_in[8];
    const float* beta1  = (const float*)d_in[9];
    const float* gamma2 = (const float*)d_in[10];
    const float* beta2  = (const float*)d_in[11];
    float* out = (float*)d_out;

    char* w = (char*)d_ws;
    _Float16* qkv16 = (_Float16*)(w + 0);
    _Float16* h1    = (_Float16*)(w + 0);
    _Float16* Vt    = (_Float16*)(w + 67108864);
    _Float16* xn    = (_Float16*)(w + 83886080);
    _Float16* ao    = (_Float16*)(w + 100663296);
    _Float16* wqT   = (_Float16*)(w + 117440512);
    _Float16* woT   = (_Float16*)(w + 123731968);
    _Float16* w1T   = (_Float16*)(w + 125829120);
    _Float16* w2T   = (_Float16*)(w + 134217728);

    dim3 blk(256);

    wprep_kernel<<<dim3(3072/32, 1024/32), blk, 0, stream>>>(w_qkv, wqT, 1024, 3072);
    wprep_kernel<<<dim3(1024/32, 1024/32), blk, 0, stream>>>(w_out, woT, 1024, 1024);
    wprep_kernel<<<dim3(4096/32, 1024/32), blk, 0, stream>>>(w1,    w1T, 1024, 4096);
    wprep_kernel<<<dim3(1024/32, 4096/32), blk, 0, stream>>>(w2,    w2T, 4096, 1024);

    // 1. xn = LN(src)
    ln16_kernel<<<M_ROWS, blk, 0, stream>>>(src, gamma1, beta1, xn);
    // 2. qkv16 = xn @ w_qkv (fp16 out)
    gemm_f16<false,false,false,true><<<(M_ROWS/128)*(3072/128), blk, 0, stream>>>(
        xn, wqT, nullptr, nullptr, nullptr, qkv16, M_ROWS, 3072, 1024);
    // 2b. Vt = per-head V^T
    vrepack_kernel<<<dim3(64, 64), blk, 0, stream>>>(qkv16, Vt);
    // 3. flash attention -> ao (fp16)
    fattn_kernel<<<64 * 16, blk, 0, stream>>>(qkv16, Vt, ao);
    // 4. src2 = src + ao @ w_out + b_out -> d_out (fp32)
    gemm_f16<true,false,true,false><<<(M_ROWS/128)*(1024/128), blk, 0, stream>>>(
        ao, woT, b_out, src, out, nullptr, M_ROWS, 1024, 1024);
    // 5. x2 = LN(src2)
    ln16_kernel<<<M_ROWS, blk, 0, stream>>>(out, gamma2, beta2, xn);
    // 6. h1 = relu(x2 @ w1 + b1) (fp16)
    gemm_f16<true,true,false,true><<<(M_ROWS/128)*(4096/128), blk, 0, stream>>>(
        xn, w1T, b1, nullptr, nullptr, h1, M_ROWS, 4096, 1024);
    // 7. out = src2 + h1 @ w2 + b2 (fp32, in-place residual)
    gemm_f16<true,false,true,false><<<(M_ROWS/128)*(1024/128), blk, 0, stream>>>(
        h1, w2T, b2, out, out, nullptr, M_ROWS, 1024, 4096);
}